// Round 14
// baseline (37.781 us; speedup 1.0000x reference)
//
#include <hip/hip_runtime.h>

#define MAX_SPIKE 100000.0f

constexpr int BATCH  = 128;
constexpr int NIN    = 1024;
constexpr int MOUT   = 512;
constexpr int NSEG   = 8;             // segments == waves per block
constexpr int SEGLEN = NIN / NSEG;    // 128
constexpr int T      = 512;           // 8 waves
constexpr int CPB    = 64;            // columns per block (1 per lane)
constexpr int CH     = 8;             // chunk = 8 elements

typedef unsigned long long u64;

__device__ __forceinline__ float fastrcp(float x) {
#if __has_builtin(__builtin_amdgcn_rcpf)
    return __builtin_amdgcn_rcpf(x);   // v_rcp_f32, 1 ulp
#else
    float r; asm volatile("v_rcp_f32 %0, %1" : "=v"(r) : "v"(x)); return r;
#endif
}

// ================= fused kernel: in-block sort + two-pass scan =============
// Each block (b, cg) sorts row b in LDS (8x redundant across col-groups --
// parallel VALU/LDS work, hidden at 4 blocks/CU) then runs the two-pass
// zero-redundancy scan (r13-proven) on its 64 columns. One launch, no
// workspace, no inter-kernel bubble, no xs/ro HBM round-trip.
__global__ __launch_bounds__(T, 8) void snn_fused_kernel(const float* __restrict__ x,
                                                         const float* __restrict__ w,
                                                         float* __restrict__ out) {
    __shared__ u64 keys[NIN];                        // 8 KB (sort phase)
    __shared__ __align__(16) float xsl[NIN + 8];     // 4.1 KB sorted xs (+sentinel)
    __shared__ __align__(16) int   rol[NIN];         // 4 KB  byte offsets
    __shared__ float2 partsh[NSEG][CPB];             // 4 KB  per-seg partials
    __shared__ float  bestsh[NSEG][CPB];             // 2 KB

    const int tid  = threadIdx.x;
    const int b    = blockIdx.x >> 3;
    const int cg   = blockIdx.x & 7;
    const int seg  = tid >> 6;            // wave == segment (uniform work)
    const int lane = tid & 63;
    const unsigned mo4 = (unsigned)(cg * CPB + lane) * 4u;

    // ---------------- phase A: hybrid bitonic argsort (r13-proven) ---------
    // thread (wv,l) owns i0 = wv*128+l, i1 = i0+64. j<=32: shfl; j==64:
    // intra-thread; j>=128: LDS. key = (float_bits<<32)|index -> stable.
    {
        const int wv = seg;               // 8 waves
        const int l  = lane;
        const int i0 = wv * 128 + l;
        const int i1 = i0 + 64;

        u64 e0 = ((u64)__float_as_uint(x[b * NIN + i0]) << 32) | (unsigned)i0;
        u64 e1 = ((u64)__float_as_uint(x[b * NIN + i1]) << 32) | (unsigned)i1;

        auto CE_SHFL = [&](u64& e, int idx, int k, int j) {
            u64 p = __shfl_xor(e, j, 64);
            bool lower   = ((l & j) == 0);
            bool asc     = ((idx & k) == 0);
            bool takeMin = (lower == asc);
            bool pLess   = (p < e);
            e = (pLess == takeMin) ? p : e;
        };
        auto CE_J64 = [&](int k) {
            bool asc = ((i0 & k) == 0);
            bool sw  = asc ? (e0 > e1) : (e0 < e1);
            if (sw) { u64 t = e0; e0 = e1; e1 = t; }
        };

        for (int k = 2; k <= 64; k <<= 1)
            for (int j = k >> 1; j >= 1; j >>= 1) { CE_SHFL(e0, i0, k, j); CE_SHFL(e1, i1, k, j); }
        CE_J64(128);
        for (int j = 32; j >= 1; j >>= 1) { CE_SHFL(e0, i0, 128, j); CE_SHFL(e1, i1, 128, j); }

        for (int k = 256; k <= NIN; k <<= 1) {
            keys[i0] = e0; keys[i1] = e1;
            __syncthreads();
            for (int j = k >> 1; j >= 128; j >>= 1) {
                int idx  = ((tid & ~(j - 1)) << 1) | (tid & (j - 1));
                int part = idx | j;
                u64 a = keys[idx], c = keys[part];
                bool asc = ((idx & k) == 0);
                if (asc ? (a > c) : (a < c)) { keys[idx] = c; keys[part] = a; }
                __syncthreads();
            }
            e0 = keys[i0]; e1 = keys[i1];
            CE_J64(k);
            for (int j = 32; j >= 1; j >>= 1) { CE_SHFL(e0, i0, k, j); CE_SHFL(e1, i1, k, j); }
        }

        xsl[i0] = __uint_as_float((unsigned)(e0 >> 32));
        xsl[i1] = __uint_as_float((unsigned)(e1 >> 32));
        rol[i0] = (int)(unsigned)(e0 & 0xFFFFFFFFull) * (MOUT * 4);  // byte off
        rol[i1] = (int)(unsigned)(e1 & 0xFFFFFFFFull) * (MOUT * 4);
        if (tid == 0) xsl[NIN] = MAX_SPIKE;
    }
    __syncthreads();

    // ---------------- phase B: two-pass zero-redundancy scan ---------------
    // Pass 1: wave s cheap-scans ONLY its 128 elements -> partial in LDS.
    // base(s) = sum of earlier partials (O(1e-6) reassociation, bf16-
    // invisible via boundary compensation -- validated r12/r13).
    // Pass 2: screen own segment from base, with provable segment skips.
    const char* wb = (const char*)w;
    float XA[CH], XB[CH], WA[CH], WB[CH];

// read xs chunk (2x ds_read_b128) + 8 gathered weight loads
#define RDIS(X, W, c_) { const int cc_ = (c_); \
    float4 a0_ = *(const float4*)&xsl[cc_ * 8]; \
    float4 a1_ = *(const float4*)&xsl[cc_ * 8 + 4]; \
    X[0] = a0_.x; X[1] = a0_.y; X[2] = a0_.z; X[3] = a0_.w; \
    X[4] = a1_.x; X[5] = a1_.y; X[6] = a1_.z; X[7] = a1_.w; \
    int4 r0_ = *(const int4*)&rol[cc_ * 8]; \
    int4 r1_ = *(const int4*)&rol[cc_ * 8 + 4]; \
    W[0] = *(const float*)(wb + ((unsigned)r0_.x + mo4)); \
    W[1] = *(const float*)(wb + ((unsigned)r0_.y + mo4)); \
    W[2] = *(const float*)(wb + ((unsigned)r0_.z + mo4)); \
    W[3] = *(const float*)(wb + ((unsigned)r0_.w + mo4)); \
    W[4] = *(const float*)(wb + ((unsigned)r1_.x + mo4)); \
    W[5] = *(const float*)(wb + ((unsigned)r1_.y + mo4)); \
    W[6] = *(const float*)(wb + ((unsigned)r1_.z + mo4)); \
    W[7] = *(const float*)(wb + ((unsigned)r1_.w + mo4)); }

    const int c0 = seg * (SEGLEN / CH);   // seg*16
    const int c1 = c0 + SEGLEN / CH;      // +16

    // ---- pass 1: cheap partial over own segment only
    float pc = 0.0f, pi = 0.0f;
#define CHEAP8(X, W) { _Pragma("unroll") \
    for (int u = 0; u < CH; ++u) { \
        float ww = W[u]; \
        pc += ww; pi = fmaf(ww, X[u], pi); } }

    RDIS(XA, WA, c0);
    for (int c = c0; c < c1; c += 2) {
        RDIS(XB, WB, c + 1);
        CHEAP8(XA, WA);
        if (c + 2 < c1) RDIS(XA, WA, c + 2);
        CHEAP8(XB, WB);
    }
#undef CHEAP8

    partsh[seg][lane] = make_float2(pc, pi);
    __syncthreads();

    // ---- base = ascending sum of earlier segments' partials
    float bc = 0.0f, bi = 0.0f;
    for (int t = 0; t < seg; ++t) {
        float2 p = partsh[t][lane];
        bc += p.x; bi += p.y;
    }

    float best = MAX_SPIKE;
    {
        const float xn0  = xsl[c0 * 8];              // xs[seg*128]
        const float endc = bc + pc;
        // pre: wcum < 1 through the whole segment -> no candidate possible.
        // post: base q below window bottom (margin 1e-3) -> q stays below
        //       every later window (q' in (q, xs[n+1]) whenever q < xs[n+1]).
        bool pre  = (endc < 1.0f);
        bool post = (bc > 1.0f) && (bi < (xn0 * (bc - 1.0f)) * (1.0f - 1e-3f));
        bool skip = (__all((int)(pre || post)) != 0);

        if (!skip) {
            float wc = bc, wi = bi;
            // Branchless screen: d=max(wc-1,1e-10); q=wi*rcp(d) (1 ulp);
            // ok = wc>=1 && q in [xv,xl]  (wc>=1 kills the xv=0^wi=0 edge).
#define SCREEN8(X, W, XL8) { _Pragma("unroll") \
    for (int u = 0; u < CH; ++u) { \
        float xv = X[u]; \
        float xl = (u < CH - 1) ? X[u + 1] : (XL8); \
        float ww = W[u]; \
        wc += ww; wi = fmaf(ww, xv, wi); \
        float d = fmaxf(wc - 1.0f, 1e-10f); \
        float q = wi * fastrcp(d); \
        bool ok = (wc >= 1.0f) && (q >= xv) && (q <= xl); \
        best = ok ? fminf(best, q) : best; } }

            RDIS(XA, WA, c0);
            for (int c = c0; c < c1; c += 2) {
                RDIS(XB, WB, c + 1);
                SCREEN8(XA, WA, XB[0]);
                const bool more = (c + 2 < c1);
                if (more) RDIS(XA, WA, c + 2);
                float xlB = more ? XA[0] : xsl[(c + 2) * 8];  // sentinel-safe
                SCREEN8(XB, WB, xlB);
            }
#undef SCREEN8
        }
    }
#undef RDIS

    bestsh[seg][lane] = best;
    __syncthreads();
    if (tid < CPB) {
        float r = bestsh[0][tid];
        #pragma unroll
        for (int s = 1; s < NSEG; ++s) r = fminf(r, bestsh[s][tid]);
        out[b * MOUT + cg * CPB + tid] = r;
    }
}

extern "C" void kernel_launch(void* const* d_in, const int* in_sizes, int n_in,
                              void* d_out, int out_size, void* d_ws, size_t ws_size,
                              hipStream_t stream) {
    (void)in_sizes; (void)n_in; (void)out_size; (void)d_ws; (void)ws_size;
    const float* x = (const float*)d_in[0];
    const float* w = (const float*)d_in[1];
    float* out = (float*)d_out;

    hipLaunchKernelGGL(snn_fused_kernel, dim3(BATCH * (MOUT / CPB)), dim3(T),
                       0, stream, x, w, out);
}

// Round 15
// 36.883 us; speedup vs baseline: 1.0243x; 1.0243x over previous
//
#include <hip/hip_runtime.h>

#define MAX_SPIKE 100000.0f

constexpr int BATCH  = 128;
constexpr int NIN    = 1024;
constexpr int MOUT   = 512;
constexpr int NSEG   = 8;             // segments == waves per block
constexpr int SEGLEN = NIN / NSEG;    // 128
constexpr int T      = 512;           // 8 waves
constexpr int CPB    = 128;           // columns per block (2 per lane)
constexpr int CH     = 8;             // chunk = 8 elements

typedef unsigned long long u64;

__device__ __forceinline__ float fastrcp(float x) {
#if __has_builtin(__builtin_amdgcn_rcpf)
    return __builtin_amdgcn_rcpf(x);   // v_rcp_f32, 1 ulp
#else
    float r; asm volatile("v_rcp_f32 %0, %1" : "=v"(r) : "v"(x)); return r;
#endif
}

// ================= fused kernel: in-block sort + two-pass scan =============
// 512 blocks (4 col-groups/row): sort redundancy 4x (was 8x in r14), scan
// metadata amortized over 2 cols/lane. Two-pass zero-redundancy scan with
// reassociated segment handoff (bf16-invisible, validated r12/r13) and
// pre/post segment skips. Screen has no trans-op on the common path; the
// q computation runs under a rarely-taken exec-mask branch.
__global__ __launch_bounds__(T, 4) void snn_fused_kernel(const float* __restrict__ x,
                                                         const float* __restrict__ w,
                                                         float* __restrict__ out) {
    __shared__ u64 keys[NIN];                        // 8 KB (sort phase)
    __shared__ __align__(16) float xsl[NIN + 8];     // 4.1 KB sorted xs (+sentinel)
    __shared__ __align__(16) int   rol[NIN];         // 4 KB  byte offsets
    __shared__ float4 partsh[NSEG][CPB / 2];         // 8 KB  (pc0,pi0,pc1,pi1)
    __shared__ float  bestsh[NSEG][CPB];             // 4 KB

    const int tid  = threadIdx.x;
    const int b    = blockIdx.x >> 2;
    const int cg   = blockIdx.x & 3;
    const int seg  = tid >> 6;            // wave == segment (uniform work)
    const int lane = tid & 63;
    const unsigned mo4 = (unsigned)(cg * CPB + lane) * 4u;  // col0; col1 = +256B

    // ---------------- phase A: hybrid bitonic argsort (r13/r14-proven) -----
    {
        const int wv = seg;
        const int l  = lane;
        const int i0 = wv * 128 + l;
        const int i1 = i0 + 64;

        u64 e0 = ((u64)__float_as_uint(x[b * NIN + i0]) << 32) | (unsigned)i0;
        u64 e1 = ((u64)__float_as_uint(x[b * NIN + i1]) << 32) | (unsigned)i1;

        auto CE_SHFL = [&](u64& e, int idx, int k, int j) {
            u64 p = __shfl_xor(e, j, 64);
            bool lower   = ((l & j) == 0);
            bool asc     = ((idx & k) == 0);
            bool takeMin = (lower == asc);
            bool pLess   = (p < e);
            e = (pLess == takeMin) ? p : e;
        };
        auto CE_J64 = [&](int k) {
            bool asc = ((i0 & k) == 0);
            bool sw  = asc ? (e0 > e1) : (e0 < e1);
            if (sw) { u64 t = e0; e0 = e1; e1 = t; }
        };

        for (int k = 2; k <= 64; k <<= 1)
            for (int j = k >> 1; j >= 1; j >>= 1) { CE_SHFL(e0, i0, k, j); CE_SHFL(e1, i1, k, j); }
        CE_J64(128);
        for (int j = 32; j >= 1; j >>= 1) { CE_SHFL(e0, i0, 128, j); CE_SHFL(e1, i1, 128, j); }

        for (int k = 256; k <= NIN; k <<= 1) {
            keys[i0] = e0; keys[i1] = e1;
            __syncthreads();
            for (int j = k >> 1; j >= 128; j >>= 1) {
                int idx  = ((tid & ~(j - 1)) << 1) | (tid & (j - 1));
                int part = idx | j;
                u64 a = keys[idx], c = keys[part];
                bool asc = ((idx & k) == 0);
                if (asc ? (a > c) : (a < c)) { keys[idx] = c; keys[part] = a; }
                __syncthreads();
            }
            e0 = keys[i0]; e1 = keys[i1];
            CE_J64(k);
            for (int j = 32; j >= 1; j >>= 1) { CE_SHFL(e0, i0, k, j); CE_SHFL(e1, i1, k, j); }
        }

        xsl[i0] = __uint_as_float((unsigned)(e0 >> 32));
        xsl[i1] = __uint_as_float((unsigned)(e1 >> 32));
        rol[i0] = (int)(unsigned)(e0 & 0xFFFFFFFFull) * (MOUT * 4);  // byte off
        rol[i1] = (int)(unsigned)(e1 & 0xFFFFFFFFull) * (MOUT * 4);
        if (tid == 0) xsl[NIN] = MAX_SPIKE;
    }
    __syncthreads();

    // ---------------- phase B: two-pass zero-redundancy scan, 2 cols -------
    const char* wb = (const char*)w;
    float XA[CH], XB[CH], A0[CH], A1[CH], B0[CH], B1[CH];

// read xs chunk (2x ds_read_b128) + ro (2x b128) + 16 gathered weight loads
#define RDIS(X, V0, V1, c_) { const int cc_ = (c_); \
    float4 a0_ = *(const float4*)&xsl[cc_ * 8]; \
    float4 a1_ = *(const float4*)&xsl[cc_ * 8 + 4]; \
    X[0] = a0_.x; X[1] = a0_.y; X[2] = a0_.z; X[3] = a0_.w; \
    X[4] = a1_.x; X[5] = a1_.y; X[6] = a1_.z; X[7] = a1_.w; \
    int4 r0_ = *(const int4*)&rol[cc_ * 8]; \
    int4 r1_ = *(const int4*)&rol[cc_ * 8 + 4]; \
    V0[0] = *(const float*)(wb + ((unsigned)r0_.x + mo4)); \
    V1[0] = *(const float*)(wb + ((unsigned)r0_.x + mo4 + 256u)); \
    V0[1] = *(const float*)(wb + ((unsigned)r0_.y + mo4)); \
    V1[1] = *(const float*)(wb + ((unsigned)r0_.y + mo4 + 256u)); \
    V0[2] = *(const float*)(wb + ((unsigned)r0_.z + mo4)); \
    V1[2] = *(const float*)(wb + ((unsigned)r0_.z + mo4 + 256u)); \
    V0[3] = *(const float*)(wb + ((unsigned)r0_.w + mo4)); \
    V1[3] = *(const float*)(wb + ((unsigned)r0_.w + mo4 + 256u)); \
    V0[4] = *(const float*)(wb + ((unsigned)r1_.x + mo4)); \
    V1[4] = *(const float*)(wb + ((unsigned)r1_.x + mo4 + 256u)); \
    V0[5] = *(const float*)(wb + ((unsigned)r1_.y + mo4)); \
    V1[5] = *(const float*)(wb + ((unsigned)r1_.y + mo4 + 256u)); \
    V0[6] = *(const float*)(wb + ((unsigned)r1_.z + mo4)); \
    V1[6] = *(const float*)(wb + ((unsigned)r1_.z + mo4 + 256u)); \
    V0[7] = *(const float*)(wb + ((unsigned)r1_.w + mo4)); \
    V1[7] = *(const float*)(wb + ((unsigned)r1_.w + mo4 + 256u)); }

    const int c0 = seg * (SEGLEN / CH);   // seg*16
    const int c1 = c0 + SEGLEN / CH;      // +16

    // ---- pass 1: cheap partials over own segment only (both cols)
    float pc0 = 0.0f, pi0 = 0.0f, pc1 = 0.0f, pi1 = 0.0f;
#define CHEAP8(X, V0, V1) { _Pragma("unroll") \
    for (int u = 0; u < CH; ++u) { \
        float xv = X[u]; \
        float w0 = V0[u], w1 = V1[u]; \
        pc0 += w0; pi0 = fmaf(w0, xv, pi0); \
        pc1 += w1; pi1 = fmaf(w1, xv, pi1); } }

    RDIS(XA, A0, A1, c0);
    for (int c = c0; c < c1; c += 2) {
        RDIS(XB, B0, B1, c + 1);
        CHEAP8(XA, A0, A1);
        if (c + 2 < c1) RDIS(XA, A0, A1, c + 2);
        CHEAP8(XB, B0, B1);
    }
#undef CHEAP8

    partsh[seg][lane] = make_float4(pc0, pi0, pc1, pi1);
    __syncthreads();

    // ---- base = ascending sum of earlier segments' partials
    float bc0 = 0.0f, bi0 = 0.0f, bc1 = 0.0f, bi1 = 0.0f;
    for (int t = 0; t < seg; ++t) {
        float4 p = partsh[t][lane];
        bc0 += p.x; bi0 += p.y; bc1 += p.z; bi1 += p.w;
    }

    float best0 = MAX_SPIKE, best1 = MAX_SPIKE;
    {
        const float xn0 = xsl[c0 * 8];               // xs[seg*128]
        // pre: wcum < 1 through the segment -> no candidate possible.
        // post: base q below window bottom (margin 1e-3) -> stays below forever.
        bool ok_skip0 = ((bc0 + pc0) < 1.0f) ||
                        ((bc0 > 1.0f) && (bi0 < (xn0 * (bc0 - 1.0f)) * (1.0f - 1e-3f)));
        bool ok_skip1 = ((bc1 + pc1) < 1.0f) ||
                        ((bc1 > 1.0f) && (bi1 < (xn0 * (bc1 - 1.0f)) * (1.0f - 1e-3f)));
        bool skip = (__all((int)(ok_skip0 && ok_skip1)) != 0);

        if (!skip) {
            float wc0 = bc0, wi0 = bi0, wc1 = bc1, wi1 = bi1;
            // Common path: bounds test on wi vs [xv*d, xl*d] (no trans op).
            // Rare branch computes q via v_rcp (1 ulp, validated r12/r13).
            // wc>=1 kept explicitly (kills the xv=0 ^ wi=0 spurious edge).
#define SCREEN8(X, V0, V1, XL8) { _Pragma("unroll") \
    for (int u = 0; u < CH; ++u) { \
        float xv = X[u]; \
        float xl = (u < CH - 1) ? X[u + 1] : (XL8); \
        float w0 = V0[u], w1 = V1[u]; \
        wc0 += w0; wi0 = fmaf(w0, xv, wi0); \
        wc1 += w1; wi1 = fmaf(w1, xv, wi1); \
        float d0 = wc0 - 1.0f; \
        float d1 = wc1 - 1.0f; \
        bool ok0 = (wc0 >= 1.0f) && (wi0 >= xv * d0) && (wi0 <= xl * d0); \
        bool ok1 = (wc1 >= 1.0f) && (wi1 >= xv * d1) && (wi1 <= xl * d1); \
        if (ok0 | ok1) { \
            float q0 = wi0 * fastrcp(fmaxf(d0, 1e-10f)); \
            float q1 = wi1 * fastrcp(fmaxf(d1, 1e-10f)); \
            best0 = ok0 ? fminf(best0, q0) : best0; \
            best1 = ok1 ? fminf(best1, q1) : best1; \
        } } }

            RDIS(XA, A0, A1, c0);
            for (int c = c0; c < c1; c += 2) {
                RDIS(XB, B0, B1, c + 1);
                SCREEN8(XA, A0, A1, XB[0]);
                const bool more = (c + 2 < c1);
                if (more) RDIS(XA, A0, A1, c + 2);
                float xlB = more ? XA[0] : xsl[(c + 2) * 8];  // sentinel-safe
                SCREEN8(XB, B0, B1, xlB);
            }
#undef SCREEN8
        }
    }
#undef RDIS

    bestsh[seg][lane]      = best0;
    bestsh[seg][lane + 64] = best1;
    __syncthreads();
    if (tid < CPB) {
        float r = bestsh[0][tid];
        #pragma unroll
        for (int s = 1; s < NSEG; ++s) r = fminf(r, bestsh[s][tid]);
        out[b * MOUT + cg * CPB + tid] = r;
    }
}

extern "C" void kernel_launch(void* const* d_in, const int* in_sizes, int n_in,
                              void* d_out, int out_size, void* d_ws, size_t ws_size,
                              hipStream_t stream) {
    (void)in_sizes; (void)n_in; (void)out_size; (void)d_ws; (void)ws_size;
    const float* x = (const float*)d_in[0];
    const float* w = (const float*)d_in[1];
    float* out = (float*)d_out;

    hipLaunchKernelGGL(snn_fused_kernel, dim3(BATCH * (MOUT / CPB)), dim3(T),
                       0, stream, x, w, out);
}

// Round 16
// 33.675 us; speedup vs baseline: 1.1219x; 1.0953x over previous
//
#include <hip/hip_runtime.h>

#define MAX_SPIKE 100000.0f

constexpr int BATCH  = 128;
constexpr int NIN    = 1024;
constexpr int MOUT   = 512;
constexpr int NSEG   = 16;            // segments == waves per block
constexpr int SEGLEN = NIN / NSEG;    // 64
constexpr int T      = 1024;          // 16 waves
constexpr int CPB    = 128;           // columns per block (2 per lane)
constexpr int CH     = 8;             // chunk = 8 elements

typedef unsigned long long u64;

__device__ __forceinline__ float fastrcp(float x) {
#if __has_builtin(__builtin_amdgcn_rcpf)
    return __builtin_amdgcn_rcpf(x);   // v_rcp_f32, 1 ulp
#else
    float r; asm volatile("v_rcp_f32 %0, %1" : "=v"(r) : "v"(x)); return r;
#endif
}

// ================= fused kernel: in-block sort + two-pass scan =============
// T=1024 / 16 segment-waves decouples work (2 cols/lane) from occupancy
// (8 waves/SIMD; r15 was grid-limited to 4). Sort: 1-elem-per-thread hybrid
// bitonic (j<=32 shfl, j>=64 LDS, 10 LDS stages). Scan: two-pass zero-
// redundancy with reassociated handoff (bf16-invisible, validated r12-r15)
// + pre/post segment skips; screen common path has no trans op.
__global__ __launch_bounds__(T, 8) void snn_fused_kernel(const float* __restrict__ x,
                                                         const float* __restrict__ w,
                                                         float* __restrict__ out) {
    __shared__ u64 keys[NIN];                        // 8 KB (sort phase)
    __shared__ __align__(16) float xsl[NIN + 8];     // 4.1 KB sorted xs (+sentinel)
    __shared__ __align__(16) int   rol[NIN];         // 4 KB  byte offsets
    __shared__ float4 partsh[NSEG][64];              // 16 KB (pc0,pi0,pc1,pi1)
    __shared__ float  bestsh[NSEG][CPB];             // 8 KB

    const int tid  = threadIdx.x;
    const int b    = blockIdx.x >> 2;
    const int cg   = blockIdx.x & 3;
    const int seg  = tid >> 6;            // wave == segment (uniform work)
    const int lane = tid & 63;
    const unsigned mo4 = (unsigned)(cg * CPB + lane) * 4u;  // col0; col1 = +256B

    // ---------------- phase A: 1-elem/thread hybrid bitonic argsort --------
    // element i == tid. key = (float_bits<<32)|i : x >= 0 so uint order ==
    // float order; index low bits -> distinct keys -> stable argsort.
    {
        u64 e = ((u64)__float_as_uint(x[b * NIN + tid]) << 32) | (unsigned)tid;

        auto CE_SHFL = [&](int k, int j) {           // partner in same wave (j<=32)
            u64 p = __shfl_xor(e, j, 64);
            bool takeMin = (((tid & j) == 0) == ((tid & k) == 0));
            e = ((p < e) == takeMin) ? p : e;
        };
        auto CE_LDS = [&](int k, int j) {            // partner across waves (j>=64)
            keys[tid] = e;
            __syncthreads();
            u64 p = keys[tid ^ j];
            bool takeMin = (((tid & j) == 0) == ((tid & k) == 0));
            e = ((p < e) == takeMin) ? p : e;
            __syncthreads();
        };

        for (int k = 2; k <= 64; k <<= 1)
            for (int j = k >> 1; j >= 1; j >>= 1) CE_SHFL(k, j);
        for (int k = 128; k <= NIN; k <<= 1) {
            for (int j = k >> 1; j >= 64; j >>= 1) CE_LDS(k, j);
            for (int j = 32; j >= 1; j >>= 1) CE_SHFL(k, j);
        }

        xsl[tid] = __uint_as_float((unsigned)(e >> 32));
        rol[tid] = (int)(unsigned)(e & 0xFFFFFFFFull) * (MOUT * 4);  // byte off
        if (tid == 0) xsl[NIN] = MAX_SPIKE;
    }
    __syncthreads();

    // ---------------- phase B: two-pass zero-redundancy scan, 2 cols -------
    const char* wb = (const char*)w;
    float XA[CH], XB[CH], A0[CH], A1[CH], B0[CH], B1[CH];

// read xs chunk (2x ds_read_b128) + ro (2x b128) + 16 gathered weight loads
#define RDIS(X, V0, V1, c_) { const int cc_ = (c_); \
    float4 a0_ = *(const float4*)&xsl[cc_ * 8]; \
    float4 a1_ = *(const float4*)&xsl[cc_ * 8 + 4]; \
    X[0] = a0_.x; X[1] = a0_.y; X[2] = a0_.z; X[3] = a0_.w; \
    X[4] = a1_.x; X[5] = a1_.y; X[6] = a1_.z; X[7] = a1_.w; \
    int4 r0_ = *(const int4*)&rol[cc_ * 8]; \
    int4 r1_ = *(const int4*)&rol[cc_ * 8 + 4]; \
    V0[0] = *(const float*)(wb + ((unsigned)r0_.x + mo4)); \
    V1[0] = *(const float*)(wb + ((unsigned)r0_.x + mo4 + 256u)); \
    V0[1] = *(const float*)(wb + ((unsigned)r0_.y + mo4)); \
    V1[1] = *(const float*)(wb + ((unsigned)r0_.y + mo4 + 256u)); \
    V0[2] = *(const float*)(wb + ((unsigned)r0_.z + mo4)); \
    V1[2] = *(const float*)(wb + ((unsigned)r0_.z + mo4 + 256u)); \
    V0[3] = *(const float*)(wb + ((unsigned)r0_.w + mo4)); \
    V1[3] = *(const float*)(wb + ((unsigned)r0_.w + mo4 + 256u)); \
    V0[4] = *(const float*)(wb + ((unsigned)r1_.x + mo4)); \
    V1[4] = *(const float*)(wb + ((unsigned)r1_.x + mo4 + 256u)); \
    V0[5] = *(const float*)(wb + ((unsigned)r1_.y + mo4)); \
    V1[5] = *(const float*)(wb + ((unsigned)r1_.y + mo4 + 256u)); \
    V0[6] = *(const float*)(wb + ((unsigned)r1_.z + mo4)); \
    V1[6] = *(const float*)(wb + ((unsigned)r1_.z + mo4 + 256u)); \
    V0[7] = *(const float*)(wb + ((unsigned)r1_.w + mo4)); \
    V1[7] = *(const float*)(wb + ((unsigned)r1_.w + mo4 + 256u)); }

    const int c0 = seg * (SEGLEN / CH);   // seg*8
    const int c1 = c0 + SEGLEN / CH;      // +8

    // ---- pass 1: cheap partials over own segment only (both cols)
    float pc0 = 0.0f, pi0 = 0.0f, pc1 = 0.0f, pi1 = 0.0f;
#define CHEAP8(X, V0, V1) { _Pragma("unroll") \
    for (int u = 0; u < CH; ++u) { \
        float xv = X[u]; \
        float w0 = V0[u], w1 = V1[u]; \
        pc0 += w0; pi0 = fmaf(w0, xv, pi0); \
        pc1 += w1; pi1 = fmaf(w1, xv, pi1); } }

    RDIS(XA, A0, A1, c0);
    for (int c = c0; c < c1; c += 2) {
        RDIS(XB, B0, B1, c + 1);
        CHEAP8(XA, A0, A1);
        if (c + 2 < c1) RDIS(XA, A0, A1, c + 2);
        CHEAP8(XB, B0, B1);
    }
#undef CHEAP8

    partsh[seg][lane] = make_float4(pc0, pi0, pc1, pi1);
    __syncthreads();

    // ---- base = ascending sum of earlier segments' partials
    float bc0 = 0.0f, bi0 = 0.0f, bc1 = 0.0f, bi1 = 0.0f;
    for (int t = 0; t < seg; ++t) {
        float4 p = partsh[t][lane];
        bc0 += p.x; bi0 += p.y; bc1 += p.z; bi1 += p.w;
    }

    float best0 = MAX_SPIKE, best1 = MAX_SPIKE;
    {
        const float xn0 = xsl[c0 * 8];               // xs[seg*64]
        // pre: wcum < 1 through the segment -> no candidate possible.
        // post: base q below window bottom (margin 1e-3) -> stays below forever
        //       (q' in (q, xs[n+1]) whenever q < xs[n+1]).
        bool ok_skip0 = ((bc0 + pc0) < 1.0f) ||
                        ((bc0 > 1.0f) && (bi0 < (xn0 * (bc0 - 1.0f)) * (1.0f - 1e-3f)));
        bool ok_skip1 = ((bc1 + pc1) < 1.0f) ||
                        ((bc1 > 1.0f) && (bi1 < (xn0 * (bc1 - 1.0f)) * (1.0f - 1e-3f)));
        bool skip = (__all((int)(ok_skip0 && ok_skip1)) != 0);

        if (!skip) {
            float wc0 = bc0, wi0 = bi0, wc1 = bc1, wi1 = bi1;
            // Common path: bounds test on wi vs [xv*d, xl*d] (no trans op).
            // Rare branch computes q via v_rcp (1 ulp, validated r12-r15).
            // wc>=1 kept explicitly (kills the xv=0 ^ wi=0 spurious edge).
#define SCREEN8(X, V0, V1, XL8) { _Pragma("unroll") \
    for (int u = 0; u < CH; ++u) { \
        float xv = X[u]; \
        float xl = (u < CH - 1) ? X[u + 1] : (XL8); \
        float w0 = V0[u], w1 = V1[u]; \
        wc0 += w0; wi0 = fmaf(w0, xv, wi0); \
        wc1 += w1; wi1 = fmaf(w1, xv, wi1); \
        float d0 = wc0 - 1.0f; \
        float d1 = wc1 - 1.0f; \
        bool ok0 = (wc0 >= 1.0f) && (wi0 >= xv * d0) && (wi0 <= xl * d0); \
        bool ok1 = (wc1 >= 1.0f) && (wi1 >= xv * d1) && (wi1 <= xl * d1); \
        if (ok0 | ok1) { \
            float q0 = wi0 * fastrcp(fmaxf(d0, 1e-10f)); \
            float q1 = wi1 * fastrcp(fmaxf(d1, 1e-10f)); \
            best0 = ok0 ? fminf(best0, q0) : best0; \
            best1 = ok1 ? fminf(best1, q1) : best1; \
        } } }

            RDIS(XA, A0, A1, c0);
            for (int c = c0; c < c1; c += 2) {
                RDIS(XB, B0, B1, c + 1);
                SCREEN8(XA, A0, A1, XB[0]);
                const bool more = (c + 2 < c1);
                if (more) RDIS(XA, A0, A1, c + 2);
                float xlB = more ? XA[0] : xsl[(c + 2) * 8];  // sentinel-safe
                SCREEN8(XB, B0, B1, xlB);
            }
#undef SCREEN8
        }
    }
#undef RDIS

    bestsh[seg][lane]      = best0;
    bestsh[seg][lane + 64] = best1;
    __syncthreads();
    if (tid < CPB) {
        float r = bestsh[0][tid];
        #pragma unroll
        for (int s = 1; s < NSEG; ++s) r = fminf(r, bestsh[s][tid]);
        out[b * MOUT + cg * CPB + tid] = r;
    }
}

extern "C" void kernel_launch(void* const* d_in, const int* in_sizes, int n_in,
                              void* d_out, int out_size, void* d_ws, size_t ws_size,
                              hipStream_t stream) {
    (void)in_sizes; (void)n_in; (void)out_size; (void)d_ws; (void)ws_size;
    const float* x = (const float*)d_in[0];
    const float* w = (const float*)d_in[1];
    float* out = (float*)d_out;

    hipLaunchKernelGGL(snn_fused_kernel, dim3(BATCH * (MOUT / CPB)), dim3(T),
                       0, stream, x, w, out);
}